// Round 9
// baseline (842.895 us; speedup 1.0000x reference)
//
#include <hip/hip_runtime.h>
#include <math.h>

// ---------------- problem constants ----------------
#define Bn 4
#define Tn 8
#define Hn 120
#define Wn 160
#define HWn (Hn * Wn)
#define NON_SEMn 4
#define CATn 16
#define MAP_CHn 20
#define FEAT_CHn 24
#define LOCAL_Mn 240
#define GLOBAL_Mn 960
#define M2n (LOCAL_Mn * LOCAL_Mn)
#define TBMn (Tn * Bn * M2n)                  // 1,843,200 cells
#define Pn (Tn * Bn * HWn)                    // 614,400 pixels
#define NTILE_SCAN 1800                       // TBMn / 1024
#define UPD_BLKS ((Bn * M2n + 255) / 256)     // 900
#define PROJ_BLKS ((Pn + 255) / 256)          // 2400
#define GMAP_BLKS ((Bn * MAP_CHn * GLOBAL_Mn * GLOBAL_Mn / 4 + 255) / 256) // 72000

#define DEG2RADf ((float)0.017453292519943295)

typedef float vf4 __attribute__((ext_vector_type(4)));  // NT-builtin-compatible

// output layout (float element offsets into d_out)
#define OUT_FEATS 0
#define OUT_LMAP  44236800
#define OUT_GMAP  48844800
#define OUT_LP    122572800
#define OUT_GP    122572896
#define OUT_BNDS  122572992
#define OUT_ORGS  122573120

// workspace layout (4-byte element offsets into d_ws)
// rec2[cell] = {packed counts (n bits0-15, obst_n bits16-30), cur(u32)} — 8B.
#define WS_CNTR   96                          // 1 uint (global segment counter)
#define WS_REC2   128                         // TBM uint2
#define WS_BSUM   (WS_REC2 + 2 * TBMn)        // 1800 tile bases, pad 2048
#define WS_CELL   (WS_BSUM + 2048)            // P int
#define WS_RECB   (WS_CELL + Pn)              // P*16 floats (binned sem records)

// ---------------- inline pose chain (exact replication of reference order) --
__device__ __forceinline__ void pose_upto(const float* __restrict__ pose_delta,
                                          const int* __restrict__ done_flags,
                                          const float* __restrict__ init_lpose,
                                          int b, int tt,
                                          float& lx, float& ly, float& lz) {
#pragma clang fp contract(off)
    lx = init_lpose[b * 3 + 0];
    ly = init_lpose[b * 3 + 1];
    lz = init_lpose[b * 3 + 2];
    for (int t = 0; t <= tt; t++) {
        if (done_flags[b * Tn + t]) { lx = 600.0f; ly = 600.0f; lz = 0.0f; }
        float th = lz * DEG2RADf;
        float c = cosf(th), s = sinf(th);
        float d0 = pose_delta[(b * Tn + t) * 3 + 0];
        float d1 = pose_delta[(b * Tn + t) * 3 + 1];
        float d2 = pose_delta[(b * Tn + t) * 3 + 2];
        lx = lx + (d0 * c - d1 * s);
        ly = ly + (d0 * s + d1 * c);
        lz = lz + d2;
    }
}

// ---------------- fused project + gmap-outside kernel ----------------------
// Blocks [0, PROJ_BLKS): per-pixel projection, one packed atomicAdd per pixel;
// block 0 threads 0-3 also emit the pose/bounds/origins outputs.
// Blocks [PROJ_BLKS, +GMAP_BLKS): stream the outside-window global map —
// independent BW-bound work that back-fills CUs while the atomics drain.
__global__ void __launch_bounds__(256)
proj_gmap_kernel(const float* __restrict__ obs,
                 const float* __restrict__ cam,
                 const float* __restrict__ pose_delta,
                 const int* __restrict__ done_flags,
                 const int* __restrict__ upd_flags,
                 const float* __restrict__ init_lpose,
                 const float* __restrict__ init_gpose,
                 const int* __restrict__ init_bounds,
                 const float* __restrict__ init_origins,
                 const float* __restrict__ init_gmap,
                 uint2* __restrict__ rec2,
                 int* __restrict__ cellid,
                 float* __restrict__ out_lp,
                 float* __restrict__ out_gp,
                 float* __restrict__ out_bnds,
                 float* __restrict__ out_orgs,
                 float* __restrict__ out_gmap,
                 float fx) {
#pragma clang fp contract(off)
    if (blockIdx.x >= PROJ_BLKS) {
        // ---- gmap outside-window streaming ----
        size_t i4 = (size_t)(blockIdx.x - PROJ_BLKS) * 256 + threadIdx.x;
        const size_t total4 = (size_t)Bn * MAP_CHn * GLOBAL_Mn * GLOBAL_Mn / 4;
        if (i4 >= total4) return;
        size_t f = i4 * 4;
        int gx = (int)(f % GLOBAL_Mn);
        size_t r = f / GLOBAL_Mn;
        int gy = (int)(r % GLOBAL_Mn);
        size_t bc = r / GLOBAL_Mn;
        int b = (int)(bc / MAP_CHn);
        int y1 = init_bounds[b * 4 + 0];
        int x1 = init_bounds[b * 4 + 2];
        if (gy >= y1 && gy < y1 + LOCAL_Mn && gx >= x1 && gx < x1 + LOCAL_Mn) return;
        bool anyd = false;
        for (int t = 0; t < Tn; t++) anyd |= (done_flags[b * Tn + t] != 0);
        vf4 v;
        if (anyd) {
            v = (vf4)(0.0f);
        } else {
            v = __builtin_nontemporal_load((const vf4*)(init_gmap + f));
        }
        __builtin_nontemporal_store(v, (vf4*)(out_gmap + f));
        return;
    }

    // ---- pose outputs (block 0, threads 0..3) ----
    if (blockIdx.x == 0 && threadIdx.x < Bn) {
        int b = threadIdx.x;
        float lx = init_lpose[b * 3 + 0], ly = init_lpose[b * 3 + 1], lz = init_lpose[b * 3 + 2];
        float gx = init_gpose[b * 3 + 0], gy = init_gpose[b * 3 + 1], gz = init_gpose[b * 3 + 2];
        int b0 = init_bounds[b * 4 + 0], b1 = init_bounds[b * 4 + 1];
        int b2i = init_bounds[b * 4 + 2], b3 = init_bounds[b * 4 + 3];
        float ox = init_origins[b * 3 + 0], oy = init_origins[b * 3 + 1], oz = init_origins[b * 3 + 2];
        for (int t = 0; t < Tn; t++) {
            int done = done_flags[b * Tn + t];
            int upd  = upd_flags[b * Tn + t];
            if (done) {
                lx = 600.0f; ly = 600.0f; lz = 0.0f;
                gx = 2400.0f; gy = 2400.0f; gz = 0.0f;
                b0 = 360; b1 = 600; b2i = 360; b3 = 600;
                ox = 1800.0f; oy = 1800.0f; oz = 0.0f;
            }
            float th = lz * DEG2RADf;
            float c = cosf(th), sn = sinf(th);
            float d0 = pose_delta[(b * Tn + t) * 3 + 0];
            float d1 = pose_delta[(b * Tn + t) * 3 + 1];
            float d2 = pose_delta[(b * Tn + t) * 3 + 2];
            lx = lx + (d0 * c - d1 * sn);
            ly = ly + (d0 * sn + d1 * c);
            lz = lz + d2;
            if (upd) { gx = lx + ox; gy = ly + oy; gz = lz + oz; }
            out_lp[(b * Tn + t) * 3 + 0] = lx;
            out_lp[(b * Tn + t) * 3 + 1] = ly;
            out_lp[(b * Tn + t) * 3 + 2] = lz;
            out_gp[(b * Tn + t) * 3 + 0] = gx;
            out_gp[(b * Tn + t) * 3 + 1] = gy;
            out_gp[(b * Tn + t) * 3 + 2] = gz;
            out_bnds[(b * Tn + t) * 4 + 0] = (float)b0;
            out_bnds[(b * Tn + t) * 4 + 1] = (float)b1;
            out_bnds[(b * Tn + t) * 4 + 2] = (float)b2i;
            out_bnds[(b * Tn + t) * 4 + 3] = (float)b3;
            out_orgs[(b * Tn + t) * 3 + 0] = ox;
            out_orgs[(b * Tn + t) * 3 + 1] = oy;
            out_orgs[(b * Tn + t) * 3 + 2] = oz;
        }
    }

    // ---- projection ----
    int g = blockIdx.x * 256 + threadIdx.x;
    if (g >= Pn) return;
    int p = g % HWn;
    int tb = g / HWn;
    int b = tb % Bn;
    int t = tb / Bn;
    int h = p / Wn, w = p % Wn;
    const float* ob = obs + (size_t)((b * Tn + t) * MAP_CHn) * HWn;
    float depth = ob[3 * HWn + p] * 400.0f + 50.0f;
    float u = (float)w - 80.0f;
    float v = 60.0f - (float)h;
    float px = u * depth / fx;
    float py = v * depth / fx;
    float pz = depth;
    const float* Tm = cam + (size_t)(b * Tn + t) * 16;
    float X = ((Tm[0] * px + Tm[1] * py) + Tm[2] * pz) + Tm[3];
    float Y = ((Tm[4] * px + Tm[5] * py) + Tm[6] * pz) + Tm[7];
    float Z = ((Tm[8] * px + Tm[9] * py) + Tm[10] * pz) + Tm[11];
    float x_f = Z;
    float y_l = -X;
    float z_u = Y + 88.0f;
    float lx, ly, lz;
    pose_upto(pose_delta, done_flags, init_lpose, b, t, lx, ly, lz);
    float th2 = lz * DEG2RADf;
    float c2 = cosf(th2), s2 = sinf(th2);
    float wx = (lx + x_f * c2) - y_l * s2;
    float wy = (ly + x_f * s2) + y_l * c2;
    int ix = (int)floorf(wx / 5.0f);
    int iy = (int)floorf(wy / 5.0f);
    bool valid = (depth > 25.0f) && (depth < 500.0f) &&
                 (ix >= 0) && (ix < LOCAL_Mn) && (iy >= 0) && (iy < LOCAL_Mn);
    int cell = -1;
    if (valid) {
        cell = (t * Bn + b) * M2n + iy * LOCAL_Mn + ix;
        unsigned addv = 1u + ((z_u > 25.0f && z_u < 150.0f) ? 65536u : 0u);
        atomicAdd(&rec2[cell].x, addv);   // n in bits 0-15, obst_n in 16-30
    }
    cellid[g] = cell;
}

// Scan: per-1024-cell tile local exclusive scan -> rec2[].y; tile base claimed
// with ONE atomicAdd on a global counter (segment order across tiles is
// irrelevant — only disjointness matters). No second scan pass.
__global__ void scan1_kernel(uint2* __restrict__ rec2,
                             unsigned* __restrict__ bsum,
                             unsigned* __restrict__ cntr) {
    __shared__ unsigned s[256];
    int tid = threadIdx.x;
    int base = blockIdx.x * 1024 + tid * 4;
    unsigned v0 = rec2[base].x & 0xFFFFu, v1 = rec2[base + 1].x & 0xFFFFu;
    unsigned v2 = rec2[base + 2].x & 0xFFFFu, v3 = rec2[base + 3].x & 0xFFFFu;
    unsigned tsum = v0 + v1 + v2 + v3;
    s[tid] = tsum;
    __syncthreads();
    for (int d = 1; d < 256; d <<= 1) {
        unsigned a = (tid >= d) ? s[tid - d] : 0u;
        __syncthreads();
        s[tid] += a;
        __syncthreads();
    }
    unsigned excl = s[tid] - tsum;
    if (tid == 255) bsum[blockIdx.x] = atomicAdd(cntr, s[255]);
    rec2[base].y     = excl;
    rec2[base + 1].y = excl + v0;
    rec2[base + 2].y = excl + v0 + v1;
    rec2[base + 3].y = excl + v0 + v1 + v2;
}

// Per pixel: read its 16 sem channels (coalesced plane reads) and write the
// 64B record DIRECTLY into its cell's binned segment.
__global__ void scatter_copy_kernel(const float* __restrict__ obs,
                                    const int* __restrict__ cellid,
                                    const unsigned* __restrict__ bsum,
                                    uint2* __restrict__ rec2,
                                    float* __restrict__ recb) {
    int g = blockIdx.x * blockDim.x + threadIdx.x;
    if (g >= Pn) return;
    int c = cellid[g];
    if (c < 0) return;
    int p = g % HWn;
    int tb = g / HWn;
    int b = tb % Bn;
    int t = tb / Bn;
    const float* ob = obs + (size_t)((b * Tn + t) * MAP_CHn) * HWn;
    vf4 r[4];
#pragma unroll
    for (int q = 0; q < 4; q++) {
        r[q].x = ob[(size_t)(NON_SEMn + 4 * q + 0) * HWn + p];
        r[q].y = ob[(size_t)(NON_SEMn + 4 * q + 1) * HWn + p];
        r[q].z = ob[(size_t)(NON_SEMn + 4 * q + 2) * HWn + p];
        r[q].w = ob[(size_t)(NON_SEMn + 4 * q + 3) * HWn + p];
    }
    unsigned pos = bsum[c >> 10] + atomicAdd(&rec2[c].y, 1u);
    vf4* rp = (vf4*)(recb + (size_t)pos * CATn);
#pragma unroll
    for (int q = 0; q < 4; q++)
        __builtin_nontemporal_store(r[q], rp + q);
}

// Per cell: carry lmap(20)+crop(20) in registers across T steps; sem sums
// gathered from contiguous binned segments (no atomics); pose inline.
__global__ void __launch_bounds__(256)
update_kernel(const uint2* __restrict__ rec2,
              const unsigned* __restrict__ bsum,
              const float* __restrict__ recb,
              const int* __restrict__ done_flags,
              const int* __restrict__ upd_flags,
              const float* __restrict__ pose_delta,
              const float* __restrict__ init_lpose,
              const float* __restrict__ init_lmap,
              const float* __restrict__ init_gmap,
              const int* __restrict__ init_bounds,
              float* __restrict__ out_feats,
              float* __restrict__ out_lmap,
              float* __restrict__ out_gmap) {
#pragma clang fp contract(off)
    int idx = blockIdx.x * blockDim.x + threadIdx.x;
    if (idx >= Bn * M2n) return;
    int b = idx / M2n, j = idx % M2n;
    int y = j / LOCAL_Mn, x = j % LOCAL_Mn;
    int y1 = init_bounds[b * 4 + 0];
    int x1 = init_bounds[b * 4 + 2];

    float lm[MAP_CHn], cr[MAP_CHn];
#pragma unroll
    for (int ch = 0; ch < MAP_CHn; ch++)
        lm[ch] = __builtin_nontemporal_load(init_lmap + ((size_t)(b * MAP_CHn + ch)) * M2n + j);
#pragma unroll
    for (int ch = 0; ch < MAP_CHn; ch++)
        cr[ch] = __builtin_nontemporal_load(
            init_gmap + ((size_t)(b * MAP_CHn + ch) * GLOBAL_Mn + (y1 + y)) * GLOBAL_Mn + (x1 + x));

    // incremental pose chain (exact same op order as reference)
    float lx = init_lpose[b * 3 + 0];
    float ly = init_lpose[b * 3 + 1];
    float lz = init_lpose[b * 3 + 2];

    for (int t = 0; t < Tn; t++) {
        int done = done_flags[b * Tn + t];
        int upd  = upd_flags[b * Tn + t];
        if (done) {
#pragma unroll
            for (int ch = 0; ch < MAP_CHn; ch++) { lm[ch] = 0.0f; cr[ch] = 0.0f; }
            lx = 600.0f; ly = 600.0f; lz = 0.0f;
        }
        {
            float th = lz * DEG2RADf;
            float c = cosf(th), sn = sinf(th);
            float d0 = pose_delta[(b * Tn + t) * 3 + 0];
            float d1 = pose_delta[(b * Tn + t) * 3 + 1];
            float d2p = pose_delta[(b * Tn + t) * 3 + 2];
            lx = lx + (d0 * c - d1 * sn);
            ly = ly + (d0 * sn + d1 * c);
            lz = lz + d2p;
        }
        float dxg = (float)x - lx / 5.0f;
        float dyg = (float)y - ly / 5.0f;
        float d2 = dxg * dxg + dyg * dyg;
        float agent = (d2 <= 4.0f) ? 1.0f : 0.0f;
        float close = (d2 <= 9.0f) ? 1.0f : 0.0f;

        int cell = (t * Bn + b) * M2n + j;
        uint2 rc = rec2[cell];
        unsigned n = rc.x & 0xFFFFu;
        lm[0] = fmaxf(lm[0], (rc.x >> 16) ? 1.0f : 0.0f);
        lm[1] = fmaxf(lm[1], n ? 1.0f : 0.0f);
        lm[2] = agent;
        lm[3] = fmaxf(lm[3], close);

        if (n) {
            unsigned st = bsum[cell >> 10] + rc.y - n;
            float sem[CATn];
#pragma unroll
            for (int c = 0; c < CATn; c++) sem[c] = 0.0f;
            const vf4* rp = (const vf4*)(recb + (size_t)st * CATn);
            for (unsigned k = 0; k < n; k++) {
                vf4 r0 = rp[0], r1 = rp[1], r2 = rp[2], r3 = rp[3];
                rp += 4;
                sem[0] += r0.x;  sem[1] += r0.y;  sem[2] += r0.z;  sem[3] += r0.w;
                sem[4] += r1.x;  sem[5] += r1.y;  sem[6] += r1.z;  sem[7] += r1.w;
                sem[8] += r2.x;  sem[9] += r2.y;  sem[10] += r2.z; sem[11] += r2.w;
                sem[12] += r3.x; sem[13] += r3.y; sem[14] += r3.z; sem[15] += r3.w;
            }
#pragma unroll
            for (int c = 0; c < CATn; c++)
                lm[NON_SEMn + c] = fmaxf(lm[NON_SEMn + c], fminf(fmaxf(sem[c], 0.0f), 1.0f));
        }
        if (upd) {
#pragma unroll
            for (int ch = 0; ch < MAP_CHn; ch++) cr[ch] = fmaxf(cr[ch], lm[ch]);
        }

        size_t fb = ((size_t)(b * Tn + t) * FEAT_CHn) * M2n + j;
#pragma unroll
        for (int ch = 0; ch < NON_SEMn; ch++)
            __builtin_nontemporal_store(lm[ch], out_feats + fb + (size_t)ch * M2n);
#pragma unroll
        for (int ch = 0; ch < NON_SEMn; ch++)
            __builtin_nontemporal_store(cr[ch], out_feats + fb + (size_t)(NON_SEMn + ch) * M2n);
#pragma unroll
        for (int c = 0; c < CATn; c++)
            __builtin_nontemporal_store(lm[NON_SEMn + c], out_feats + fb + (size_t)(2 * NON_SEMn + c) * M2n);
    }

#pragma unroll
    for (int ch = 0; ch < MAP_CHn; ch++)
        __builtin_nontemporal_store(lm[ch], out_lmap + ((size_t)(b * MAP_CHn + ch)) * M2n + j);
#pragma unroll
    for (int ch = 0; ch < MAP_CHn; ch++)
        __builtin_nontemporal_store(
            cr[ch], out_gmap + ((size_t)(b * MAP_CHn + ch) * GLOBAL_Mn + (y1 + y)) * GLOBAL_Mn + (x1 + x));
}

// ---------------- launch ----------------
extern "C" void kernel_launch(void* const* d_in, const int* in_sizes, int n_in,
                              void* d_out, int out_size, void* d_ws, size_t ws_size,
                              hipStream_t stream) {
    const float* obs        = (const float*)d_in[0];
    const float* pose_delta = (const float*)d_in[1];
    const int*   done_flags = (const int*)d_in[2];
    const int*   upd_flags  = (const int*)d_in[3];
    const float* cam_poses  = (const float*)d_in[4];
    const float* init_lmap  = (const float*)d_in[5];
    const float* init_gmap  = (const float*)d_in[6];
    const float* init_lpose = (const float*)d_in[7];
    const float* init_gpose = (const float*)d_in[8];
    const int*   init_bnds  = (const int*)d_in[9];
    const float* init_orgs  = (const float*)d_in[10];

    float* out = (float*)d_out;
    float* ws  = (float*)d_ws;

    unsigned* cntr   = (unsigned*)(ws + WS_CNTR);
    uint2*    rec2   = (uint2*)(ws + WS_REC2);
    unsigned* bsum   = (unsigned*)(ws + WS_BSUM);
    int*      cellid = (int*)(ws + WS_CELL);
    float*    recb   = ws + WS_RECB;

    float fx = (float)(160.0 / (2.0 * tan(79.0 * M_PI / 180.0 / 2.0)));

    // zero counter (dword 96) through rec2 (ends at 128 + 2*TBM)
    (void)hipMemsetAsync(ws + WS_CNTR, 0,
                         (size_t)(32 + 2 * TBMn) * sizeof(float), stream);

    proj_gmap_kernel<<<PROJ_BLKS + GMAP_BLKS, 256, 0, stream>>>(
        obs, cam_poses, pose_delta, done_flags, upd_flags,
        init_lpose, init_gpose, init_bnds, init_orgs, init_gmap,
        rec2, cellid,
        out + OUT_LP, out + OUT_GP, out + OUT_BNDS, out + OUT_ORGS,
        out + OUT_GMAP, fx);

    scan1_kernel<<<NTILE_SCAN, 256, 0, stream>>>(rec2, bsum, cntr);

    scatter_copy_kernel<<<PROJ_BLKS, 256, 0, stream>>>(
        obs, cellid, bsum, rec2, recb);

    update_kernel<<<UPD_BLKS, 256, 0, stream>>>(
        rec2, bsum, recb, done_flags, upd_flags, pose_delta, init_lpose,
        init_lmap, init_gmap, init_bnds,
        out + OUT_FEATS, out + OUT_LMAP, out + OUT_GMAP);
}

// Round 10
// 792.371 us; speedup vs baseline: 1.0638x; 1.0638x over previous
//
#include <hip/hip_runtime.h>
#include <math.h>

// ---------------- problem constants ----------------
#define Bn 4
#define Tn 8
#define Hn 120
#define Wn 160
#define HWn (Hn * Wn)
#define NON_SEMn 4
#define CATn 16
#define MAP_CHn 20
#define FEAT_CHn 24
#define LOCAL_Mn 240
#define GLOBAL_Mn 960
#define M2n (LOCAL_Mn * LOCAL_Mn)
#define BMn (Bn * M2n)                        // 230,400 cells per step
#define TBMn (Tn * Bn * M2n)                  // 1,843,200 cells
#define Pn (Tn * Bn * HWn)                    // 614,400 pixels
#define NTILE_SCAN 1800                       // TBMn / 1024
#define PROJ_BLKS ((Pn + 255) / 256)          // 2400
#define UPD2_BLKS ((2 * BMn + 255) / 256)     // 1800 (2 half-threads per cell)
#define GMAP_BLKS ((Bn * MAP_CHn * GLOBAL_Mn * GLOBAL_Mn / 4 + 255) / 256) // 72000

#define DEG2RADf ((float)0.017453292519943295)

typedef float vf4 __attribute__((ext_vector_type(4)));  // NT-builtin-compatible

// output layout (float element offsets into d_out)
#define OUT_FEATS 0
#define OUT_LMAP  44236800
#define OUT_GMAP  48844800
#define OUT_LP    122572800
#define OUT_GP    122572896
#define OUT_BNDS  122572992
#define OUT_ORGS  122573120

// workspace layout (4-byte element offsets into d_ws)
// rec2[cell] = {packed counts (n bits0-15, obst_n bits16-30), cur(u32)} — 8B.
#define WS_CNTR   96                          // 1 uint (global segment counter)
#define WS_REC2   128                         // TBM uint2
#define WS_BSUM   (WS_REC2 + 2 * TBMn)        // 1800 tile bases, pad 2048
#define WS_CELL   (WS_BSUM + 2048)            // P int
#define WS_RECB   (WS_CELL + Pn)              // P*16 floats (binned sem records)

// ---------------- inline pose chain (exact replication of reference order) --
__device__ __forceinline__ void pose_upto(const float* __restrict__ pose_delta,
                                          const int* __restrict__ done_flags,
                                          const float* __restrict__ init_lpose,
                                          int b, int tt,
                                          float& lx, float& ly, float& lz) {
#pragma clang fp contract(off)
    lx = init_lpose[b * 3 + 0];
    ly = init_lpose[b * 3 + 1];
    lz = init_lpose[b * 3 + 2];
    for (int t = 0; t <= tt; t++) {
        if (done_flags[b * Tn + t]) { lx = 600.0f; ly = 600.0f; lz = 0.0f; }
        float th = lz * DEG2RADf;
        float c = cosf(th), s = sinf(th);
        float d0 = pose_delta[(b * Tn + t) * 3 + 0];
        float d1 = pose_delta[(b * Tn + t) * 3 + 1];
        float d2 = pose_delta[(b * Tn + t) * 3 + 2];
        lx = lx + (d0 * c - d1 * s);
        ly = ly + (d0 * s + d1 * c);
        lz = lz + d2;
    }
}

// ---------------- project kernel ----------------
// Per-pixel projection, ONE packed atomicAdd per valid pixel; block 0
// threads 0-3 also emit the pose/bounds/origins outputs.
__global__ void __launch_bounds__(256)
project_kernel(const float* __restrict__ obs,
               const float* __restrict__ cam,
               const float* __restrict__ pose_delta,
               const int* __restrict__ done_flags,
               const int* __restrict__ upd_flags,
               const float* __restrict__ init_lpose,
               const float* __restrict__ init_gpose,
               const int* __restrict__ init_bounds,
               const float* __restrict__ init_origins,
               uint2* __restrict__ rec2,
               int* __restrict__ cellid,
               float* __restrict__ out_lp,
               float* __restrict__ out_gp,
               float* __restrict__ out_bnds,
               float* __restrict__ out_orgs,
               float fx) {
#pragma clang fp contract(off)
    if (blockIdx.x == 0 && threadIdx.x < Bn) {
        int b = threadIdx.x;
        float lx = init_lpose[b * 3 + 0], ly = init_lpose[b * 3 + 1], lz = init_lpose[b * 3 + 2];
        float gx = init_gpose[b * 3 + 0], gy = init_gpose[b * 3 + 1], gz = init_gpose[b * 3 + 2];
        int b0 = init_bounds[b * 4 + 0], b1 = init_bounds[b * 4 + 1];
        int b2i = init_bounds[b * 4 + 2], b3 = init_bounds[b * 4 + 3];
        float ox = init_origins[b * 3 + 0], oy = init_origins[b * 3 + 1], oz = init_origins[b * 3 + 2];
        for (int t = 0; t < Tn; t++) {
            int done = done_flags[b * Tn + t];
            int upd  = upd_flags[b * Tn + t];
            if (done) {
                lx = 600.0f; ly = 600.0f; lz = 0.0f;
                gx = 2400.0f; gy = 2400.0f; gz = 0.0f;
                b0 = 360; b1 = 600; b2i = 360; b3 = 600;
                ox = 1800.0f; oy = 1800.0f; oz = 0.0f;
            }
            float th = lz * DEG2RADf;
            float c = cosf(th), sn = sinf(th);
            float d0 = pose_delta[(b * Tn + t) * 3 + 0];
            float d1 = pose_delta[(b * Tn + t) * 3 + 1];
            float d2 = pose_delta[(b * Tn + t) * 3 + 2];
            lx = lx + (d0 * c - d1 * sn);
            ly = ly + (d0 * sn + d1 * c);
            lz = lz + d2;
            if (upd) { gx = lx + ox; gy = ly + oy; gz = lz + oz; }
            out_lp[(b * Tn + t) * 3 + 0] = lx;
            out_lp[(b * Tn + t) * 3 + 1] = ly;
            out_lp[(b * Tn + t) * 3 + 2] = lz;
            out_gp[(b * Tn + t) * 3 + 0] = gx;
            out_gp[(b * Tn + t) * 3 + 1] = gy;
            out_gp[(b * Tn + t) * 3 + 2] = gz;
            out_bnds[(b * Tn + t) * 4 + 0] = (float)b0;
            out_bnds[(b * Tn + t) * 4 + 1] = (float)b1;
            out_bnds[(b * Tn + t) * 4 + 2] = (float)b2i;
            out_bnds[(b * Tn + t) * 4 + 3] = (float)b3;
            out_orgs[(b * Tn + t) * 3 + 0] = ox;
            out_orgs[(b * Tn + t) * 3 + 1] = oy;
            out_orgs[(b * Tn + t) * 3 + 2] = oz;
        }
    }

    int g = blockIdx.x * 256 + threadIdx.x;
    if (g >= Pn) return;
    int p = g % HWn;
    int tb = g / HWn;
    int b = tb % Bn;
    int t = tb / Bn;
    int h = p / Wn, w = p % Wn;
    const float* ob = obs + (size_t)((b * Tn + t) * MAP_CHn) * HWn;
    float depth = ob[3 * HWn + p] * 400.0f + 50.0f;
    float u = (float)w - 80.0f;
    float v = 60.0f - (float)h;
    float px = u * depth / fx;
    float py = v * depth / fx;
    float pz = depth;
    const float* Tm = cam + (size_t)(b * Tn + t) * 16;
    float X = ((Tm[0] * px + Tm[1] * py) + Tm[2] * pz) + Tm[3];
    float Y = ((Tm[4] * px + Tm[5] * py) + Tm[6] * pz) + Tm[7];
    float Z = ((Tm[8] * px + Tm[9] * py) + Tm[10] * pz) + Tm[11];
    float x_f = Z;
    float y_l = -X;
    float z_u = Y + 88.0f;
    float lx, ly, lz;
    pose_upto(pose_delta, done_flags, init_lpose, b, t, lx, ly, lz);
    float th2 = lz * DEG2RADf;
    float c2 = cosf(th2), s2 = sinf(th2);
    float wx = (lx + x_f * c2) - y_l * s2;
    float wy = (ly + x_f * s2) + y_l * c2;
    int ix = (int)floorf(wx / 5.0f);
    int iy = (int)floorf(wy / 5.0f);
    bool valid = (depth > 25.0f) && (depth < 500.0f) &&
                 (ix >= 0) && (ix < LOCAL_Mn) && (iy >= 0) && (iy < LOCAL_Mn);
    int cell = -1;
    if (valid) {
        cell = (t * Bn + b) * M2n + iy * LOCAL_Mn + ix;
        unsigned addv = 1u + ((z_u > 25.0f && z_u < 150.0f) ? 65536u : 0u);
        atomicAdd(&rec2[cell].x, addv);   // n in bits 0-15, obst_n in 16-30
    }
    cellid[g] = cell;
}

// Scan: per-1024-cell tile local exclusive scan -> rec2[].y; tile base claimed
// with ONE atomicAdd on a global counter (segment order across tiles is
// irrelevant — only disjointness matters).
__global__ void scan1_kernel(uint2* __restrict__ rec2,
                             unsigned* __restrict__ bsum,
                             unsigned* __restrict__ cntr) {
    __shared__ unsigned s[256];
    int tid = threadIdx.x;
    int base = blockIdx.x * 1024 + tid * 4;
    unsigned v0 = rec2[base].x & 0xFFFFu, v1 = rec2[base + 1].x & 0xFFFFu;
    unsigned v2 = rec2[base + 2].x & 0xFFFFu, v3 = rec2[base + 3].x & 0xFFFFu;
    unsigned tsum = v0 + v1 + v2 + v3;
    s[tid] = tsum;
    __syncthreads();
    for (int d = 1; d < 256; d <<= 1) {
        unsigned a = (tid >= d) ? s[tid - d] : 0u;
        __syncthreads();
        s[tid] += a;
        __syncthreads();
    }
    unsigned excl = s[tid] - tsum;
    if (tid == 255) bsum[blockIdx.x] = atomicAdd(cntr, s[255]);
    rec2[base].y     = excl;
    rec2[base + 1].y = excl + v0;
    rec2[base + 2].y = excl + v0 + v1;
    rec2[base + 3].y = excl + v0 + v1 + v2;
}

// Per pixel: read its 16 sem channels (coalesced plane reads) and write the
// 64B record DIRECTLY into its cell's binned segment. REGULAR stores — the
// records are re-read by the update gather, keep them in L2.
__global__ void scatter_copy_kernel(const float* __restrict__ obs,
                                    const int* __restrict__ cellid,
                                    const unsigned* __restrict__ bsum,
                                    uint2* __restrict__ rec2,
                                    float* __restrict__ recb) {
    int g = blockIdx.x * blockDim.x + threadIdx.x;
    if (g >= Pn) return;
    int c = cellid[g];
    if (c < 0) return;
    int p = g % HWn;
    int tb = g / HWn;
    int b = tb % Bn;
    int t = tb / Bn;
    const float* ob = obs + (size_t)((b * Tn + t) * MAP_CHn) * HWn;
    vf4 r[4];
#pragma unroll
    for (int q = 0; q < 4; q++) {
        r[q].x = ob[(size_t)(NON_SEMn + 4 * q + 0) * HWn + p];
        r[q].y = ob[(size_t)(NON_SEMn + 4 * q + 1) * HWn + p];
        r[q].z = ob[(size_t)(NON_SEMn + 4 * q + 2) * HWn + p];
        r[q].w = ob[(size_t)(NON_SEMn + 4 * q + 3) * HWn + p];
    }
    unsigned pos = bsum[c >> 10] + atomicAdd(&rec2[c].y, 1u);
    vf4* rp = (vf4*)(recb + (size_t)pos * CATn);
#pragma unroll
    for (int q = 0; q < 4; q++) rp[q] = r[q];
}

// ---------------- update half (templated channel split) --------------------
// Q=0: map ch 0..11 (non-sem 0-3 + sem cats 0..7), pose/agent logic, feats
//      ch 0..15. Q=1: map ch 12..19 (sem cats 8..15), feats ch 16..23.
template <int Q>
__device__ __forceinline__ void update_half(
        int b, int j,
        const uint2* __restrict__ rec2,
        const unsigned* __restrict__ bsum,
        const float* __restrict__ recb,
        const int* __restrict__ done_flags,
        const int* __restrict__ upd_flags,
        const float* __restrict__ pose_delta,
        const float* __restrict__ init_lpose,
        const float* __restrict__ init_lmap,
        const float* __restrict__ init_gmap,
        int y1, int x1,
        float* __restrict__ out_feats,
        float* __restrict__ out_lmap,
        float* __restrict__ out_gmap) {
#pragma clang fp contract(off)
    constexpr int CH0 = Q ? 12 : 0;
    constexpr int NCH = Q ? 8 : 12;
    int y = j / LOCAL_Mn, x = j % LOCAL_Mn;

    float lm[NCH], cr[NCH];
#pragma unroll
    for (int i = 0; i < NCH; i++)
        lm[i] = __builtin_nontemporal_load(init_lmap + ((size_t)(b * MAP_CHn + CH0 + i)) * M2n + j);
#pragma unroll
    for (int i = 0; i < NCH; i++)
        cr[i] = __builtin_nontemporal_load(
            init_gmap + ((size_t)(b * MAP_CHn + CH0 + i) * GLOBAL_Mn + (y1 + y)) * GLOBAL_Mn + (x1 + x));

    // prefetch all 8 step records + segment starts (independent loads)
    uint2 rc8[Tn];
#pragma unroll
    for (int t = 0; t < Tn; t++) rc8[t] = rec2[(t * Bn + b) * M2n + j];
    unsigned st8[Tn];
#pragma unroll
    for (int t = 0; t < Tn; t++) {
        unsigned n = rc8[t].x & 0xFFFFu;
        st8[t] = bsum[((t * Bn + b) * M2n + j) >> 10] + rc8[t].y - n;
    }

    float lx = 0.0f, ly = 0.0f, lz = 0.0f;
    if (Q == 0) {
        lx = init_lpose[b * 3 + 0];
        ly = init_lpose[b * 3 + 1];
        lz = init_lpose[b * 3 + 2];
    }

    for (int t = 0; t < Tn; t++) {
        int done = done_flags[b * Tn + t];
        int upd  = upd_flags[b * Tn + t];
        if (done) {
#pragma unroll
            for (int i = 0; i < NCH; i++) { lm[i] = 0.0f; cr[i] = 0.0f; }
        }
        unsigned n = rc8[t].x & 0xFFFFu;

        if (Q == 0) {
            if (done) { lx = 600.0f; ly = 600.0f; lz = 0.0f; }
            float th = lz * DEG2RADf;
            float c = cosf(th), sn = sinf(th);
            float d0 = pose_delta[(b * Tn + t) * 3 + 0];
            float d1 = pose_delta[(b * Tn + t) * 3 + 1];
            float d2p = pose_delta[(b * Tn + t) * 3 + 2];
            lx = lx + (d0 * c - d1 * sn);
            ly = ly + (d0 * sn + d1 * c);
            lz = lz + d2p;
            float dxg = (float)x - lx / 5.0f;
            float dyg = (float)y - ly / 5.0f;
            float d2 = dxg * dxg + dyg * dyg;
            lm[0] = fmaxf(lm[0], (rc8[t].x >> 16) ? 1.0f : 0.0f);
            lm[1] = fmaxf(lm[1], n ? 1.0f : 0.0f);
            lm[2] = (d2 <= 4.0f) ? 1.0f : 0.0f;
            lm[3] = fmaxf(lm[3], (d2 <= 9.0f) ? 1.0f : 0.0f);
        }

        if (n) {
            float sem[8];
#pragma unroll
            for (int c = 0; c < 8; c++) sem[c] = 0.0f;
            const vf4* rp = (const vf4*)(recb + (size_t)st8[t] * CATn) + (Q ? 2 : 0);
            for (unsigned k = 0; k < n; k++) {
                vf4 ra = rp[0], rb = rp[1];
                rp += 4;
                sem[0] += ra.x; sem[1] += ra.y; sem[2] += ra.z; sem[3] += ra.w;
                sem[4] += rb.x; sem[5] += rb.y; sem[6] += rb.z; sem[7] += rb.w;
            }
            constexpr int L0 = Q ? 0 : 4;   // lm index of first sem channel
#pragma unroll
            for (int c = 0; c < 8; c++)
                lm[L0 + c] = fmaxf(lm[L0 + c], fminf(fmaxf(sem[c], 0.0f), 1.0f));
        }
        if (upd) {
#pragma unroll
            for (int i = 0; i < NCH; i++) cr[i] = fmaxf(cr[i], lm[i]);
        }

        size_t fb = ((size_t)(b * Tn + t) * FEAT_CHn) * M2n + j;
        if (Q == 0) {
#pragma unroll
            for (int i = 0; i < 4; i++)
                __builtin_nontemporal_store(lm[i], out_feats + fb + (size_t)i * M2n);
#pragma unroll
            for (int i = 0; i < 4; i++)
                __builtin_nontemporal_store(cr[i], out_feats + fb + (size_t)(4 + i) * M2n);
#pragma unroll
            for (int i = 0; i < 8; i++)
                __builtin_nontemporal_store(lm[4 + i], out_feats + fb + (size_t)(8 + i) * M2n);
        } else {
#pragma unroll
            for (int i = 0; i < 8; i++)
                __builtin_nontemporal_store(lm[i], out_feats + fb + (size_t)(16 + i) * M2n);
        }
    }

#pragma unroll
    for (int i = 0; i < NCH; i++)
        __builtin_nontemporal_store(lm[i], out_lmap + ((size_t)(b * MAP_CHn + CH0 + i)) * M2n + j);
#pragma unroll
    for (int i = 0; i < NCH; i++)
        __builtin_nontemporal_store(
            cr[i], out_gmap + ((size_t)(b * MAP_CHn + CH0 + i) * GLOBAL_Mn + (y1 + y)) * GLOBAL_Mn + (x1 + x));
}

// Mega kernel: blocks [0, UPD2_BLKS) run the split per-cell update (dispatched
// FIRST so the critical chain starts immediately); blocks after stream the
// outside-window global map, back-filling CUs behind the update.
__global__ void __launch_bounds__(256)
mega_kernel(const uint2* __restrict__ rec2,
            const unsigned* __restrict__ bsum,
            const float* __restrict__ recb,
            const int* __restrict__ done_flags,
            const int* __restrict__ upd_flags,
            const float* __restrict__ pose_delta,
            const float* __restrict__ init_lpose,
            const float* __restrict__ init_lmap,
            const float* __restrict__ init_gmap,
            const int* __restrict__ init_bounds,
            float* __restrict__ out_feats,
            float* __restrict__ out_lmap,
            float* __restrict__ out_gmap) {
    if (blockIdx.x >= UPD2_BLKS) {
        // ---- gmap outside-window streaming ----
        size_t i4 = (size_t)(blockIdx.x - UPD2_BLKS) * 256 + threadIdx.x;
        const size_t total4 = (size_t)Bn * MAP_CHn * GLOBAL_Mn * GLOBAL_Mn / 4;
        if (i4 >= total4) return;
        size_t f = i4 * 4;
        int gx = (int)(f % GLOBAL_Mn);
        size_t r = f / GLOBAL_Mn;
        int gy = (int)(r % GLOBAL_Mn);
        size_t bc = r / GLOBAL_Mn;
        int b = (int)(bc / MAP_CHn);
        int y1 = init_bounds[b * 4 + 0];
        int x1 = init_bounds[b * 4 + 2];
        if (gy >= y1 && gy < y1 + LOCAL_Mn && gx >= x1 && gx < x1 + LOCAL_Mn) return;
        bool anyd = false;
        for (int t = 0; t < Tn; t++) anyd |= (done_flags[b * Tn + t] != 0);
        vf4 v;
        if (anyd) {
            v = (vf4)(0.0f);
        } else {
            v = __builtin_nontemporal_load((const vf4*)(init_gmap + f));
        }
        __builtin_nontemporal_store(v, (vf4*)(out_gmap + f));
        return;
    }

    int idx = blockIdx.x * 256 + threadIdx.x;
    int q = idx / BMn;            // 0 or 1 — wave-uniform (BMn = 900*256)
    int cid = idx - q * BMn;
    int b = cid / M2n, j = cid % M2n;
    int y1 = init_bounds[b * 4 + 0];
    int x1 = init_bounds[b * 4 + 2];
    if (q == 0)
        update_half<0>(b, j, rec2, bsum, recb, done_flags, upd_flags,
                       pose_delta, init_lpose, init_lmap, init_gmap,
                       y1, x1, out_feats, out_lmap, out_gmap);
    else
        update_half<1>(b, j, rec2, bsum, recb, done_flags, upd_flags,
                       pose_delta, init_lpose, init_lmap, init_gmap,
                       y1, x1, out_feats, out_lmap, out_gmap);
}

// ---------------- launch ----------------
extern "C" void kernel_launch(void* const* d_in, const int* in_sizes, int n_in,
                              void* d_out, int out_size, void* d_ws, size_t ws_size,
                              hipStream_t stream) {
    const float* obs        = (const float*)d_in[0];
    const float* pose_delta = (const float*)d_in[1];
    const int*   done_flags = (const int*)d_in[2];
    const int*   upd_flags  = (const int*)d_in[3];
    const float* cam_poses  = (const float*)d_in[4];
    const float* init_lmap  = (const float*)d_in[5];
    const float* init_gmap  = (const float*)d_in[6];
    const float* init_lpose = (const float*)d_in[7];
    const float* init_gpose = (const float*)d_in[8];
    const int*   init_bnds  = (const int*)d_in[9];
    const float* init_orgs  = (const float*)d_in[10];

    float* out = (float*)d_out;
    float* ws  = (float*)d_ws;

    unsigned* cntr   = (unsigned*)(ws + WS_CNTR);
    uint2*    rec2   = (uint2*)(ws + WS_REC2);
    unsigned* bsum   = (unsigned*)(ws + WS_BSUM);
    int*      cellid = (int*)(ws + WS_CELL);
    float*    recb   = ws + WS_RECB;

    float fx = (float)(160.0 / (2.0 * tan(79.0 * M_PI / 180.0 / 2.0)));

    // zero counter (dword 96) through rec2 (ends at 128 + 2*TBM)
    (void)hipMemsetAsync(ws + WS_CNTR, 0,
                         (size_t)(32 + 2 * TBMn) * sizeof(float), stream);

    project_kernel<<<PROJ_BLKS, 256, 0, stream>>>(
        obs, cam_poses, pose_delta, done_flags, upd_flags,
        init_lpose, init_gpose, init_bnds, init_orgs,
        rec2, cellid,
        out + OUT_LP, out + OUT_GP, out + OUT_BNDS, out + OUT_ORGS, fx);

    scan1_kernel<<<NTILE_SCAN, 256, 0, stream>>>(rec2, bsum, cntr);

    scatter_copy_kernel<<<PROJ_BLKS, 256, 0, stream>>>(
        obs, cellid, bsum, rec2, recb);

    mega_kernel<<<UPD2_BLKS + GMAP_BLKS, 256, 0, stream>>>(
        rec2, bsum, recb, done_flags, upd_flags, pose_delta, init_lpose,
        init_lmap, init_gmap, init_bnds,
        out + OUT_FEATS, out + OUT_LMAP, out + OUT_GMAP);
}

// Round 11
// 787.051 us; speedup vs baseline: 1.0710x; 1.0068x over previous
//
#include <hip/hip_runtime.h>
#include <math.h>

// ---------------- problem constants ----------------
#define Bn 4
#define Tn 8
#define Hn 120
#define Wn 160
#define HWn (Hn * Wn)
#define NON_SEMn 4
#define CATn 16
#define MAP_CHn 20
#define FEAT_CHn 24
#define LOCAL_Mn 240
#define GLOBAL_Mn 960
#define M2n (LOCAL_Mn * LOCAL_Mn)
#define BMn (Bn * M2n)                        // 230,400 cells per step
#define TBMn (Tn * Bn * M2n)                  // 1,843,200 cells
#define Pn (Tn * Bn * HWn)                    // 614,400 pixels
#define NTILE_SCAN 1800                       // TBMn / 1024
#define PROJ_BLKS ((Pn + 255) / 256)          // 2400
#define UPD2_BLKS ((2 * BMn + 255) / 256)     // 1800 (2 half-threads per cell)
#define GMAP_TOT4 ((size_t)Bn * MAP_CHn * GLOBAL_Mn * GLOBAL_Mn / 4) // 18,432,000
#define GMAP_HALF4 (GMAP_TOT4 / 2)            // 9,216,000
#define GMAP_HBLKS ((int)((GMAP_HALF4 + 255) / 256))  // 36,000

#define DEG2RADf ((float)0.017453292519943295)

typedef float vf4 __attribute__((ext_vector_type(4)));  // NT-builtin-compatible

// output layout (float element offsets into d_out)
#define OUT_FEATS 0
#define OUT_LMAP  44236800
#define OUT_GMAP  48844800
#define OUT_LP    122572800
#define OUT_GP    122572896
#define OUT_BNDS  122572992
#define OUT_ORGS  122573120

// workspace layout (4-byte element offsets into d_ws)
// rec2[cell] = {packed counts (n bits0-15, obst_n bits16-30), cur(u32)} — 8B.
#define WS_CNTR   96                          // 1 uint (global segment counter)
#define WS_REC2   128                         // TBM uint2
#define WS_BSUM   (WS_REC2 + 2 * TBMn)        // 1800 tile bases, pad 2048
#define WS_CELL   (WS_BSUM + 2048)            // P int
#define WS_RECB   (WS_CELL + Pn)              // P*16 floats (binned sem records)

// ---------------- inline pose chain (exact replication of reference order) --
__device__ __forceinline__ void pose_upto(const float* __restrict__ pose_delta,
                                          const int* __restrict__ done_flags,
                                          const float* __restrict__ init_lpose,
                                          int b, int tt,
                                          float& lx, float& ly, float& lz) {
#pragma clang fp contract(off)
    lx = init_lpose[b * 3 + 0];
    ly = init_lpose[b * 3 + 1];
    lz = init_lpose[b * 3 + 2];
    for (int t = 0; t <= tt; t++) {
        if (done_flags[b * Tn + t]) { lx = 600.0f; ly = 600.0f; lz = 0.0f; }
        float th = lz * DEG2RADf;
        float c = cosf(th), s = sinf(th);
        float d0 = pose_delta[(b * Tn + t) * 3 + 0];
        float d1 = pose_delta[(b * Tn + t) * 3 + 1];
        float d2 = pose_delta[(b * Tn + t) * 3 + 2];
        lx = lx + (d0 * c - d1 * s);
        ly = ly + (d0 * s + d1 * c);
        lz = lz + d2;
    }
}

// ---------------- gmap outside-window copy slice ---------------------------
__device__ __forceinline__ void gmap_copy_i4(size_t i4,
                                             const int* __restrict__ init_bounds,
                                             const int* __restrict__ done_flags,
                                             const float* __restrict__ init_gmap,
                                             float* __restrict__ out_gmap) {
    size_t f = i4 * 4;
    int gx = (int)(f % GLOBAL_Mn);
    size_t r = f / GLOBAL_Mn;
    int gy = (int)(r % GLOBAL_Mn);
    size_t bc = r / GLOBAL_Mn;
    int b = (int)(bc / MAP_CHn);
    int y1 = init_bounds[b * 4 + 0];
    int x1 = init_bounds[b * 4 + 2];
    if (gy >= y1 && gy < y1 + LOCAL_Mn && gx >= x1 && gx < x1 + LOCAL_Mn) return;
    bool anyd = false;
    for (int t = 0; t < Tn; t++) anyd |= (done_flags[b * Tn + t] != 0);
    vf4 v;
    if (anyd) {
        v = (vf4)(0.0f);
    } else {
        v = __builtin_nontemporal_load((const vf4*)(init_gmap + f));
    }
    __builtin_nontemporal_store(v, (vf4*)(out_gmap + f));
}

// ---------------- project kernel ----------------
// Per-pixel projection, ONE packed atomicAdd per valid pixel; block 0
// threads 0-3 also emit the pose/bounds/origins outputs.
__global__ void __launch_bounds__(256)
project_kernel(const float* __restrict__ obs,
               const float* __restrict__ cam,
               const float* __restrict__ pose_delta,
               const int* __restrict__ done_flags,
               const int* __restrict__ upd_flags,
               const float* __restrict__ init_lpose,
               const float* __restrict__ init_gpose,
               const int* __restrict__ init_bounds,
               const float* __restrict__ init_origins,
               uint2* __restrict__ rec2,
               int* __restrict__ cellid,
               float* __restrict__ out_lp,
               float* __restrict__ out_gp,
               float* __restrict__ out_bnds,
               float* __restrict__ out_orgs,
               float fx) {
#pragma clang fp contract(off)
    if (blockIdx.x == 0 && threadIdx.x < Bn) {
        int b = threadIdx.x;
        float lx = init_lpose[b * 3 + 0], ly = init_lpose[b * 3 + 1], lz = init_lpose[b * 3 + 2];
        float gx = init_gpose[b * 3 + 0], gy = init_gpose[b * 3 + 1], gz = init_gpose[b * 3 + 2];
        int b0 = init_bounds[b * 4 + 0], b1 = init_bounds[b * 4 + 1];
        int b2i = init_bounds[b * 4 + 2], b3 = init_bounds[b * 4 + 3];
        float ox = init_origins[b * 3 + 0], oy = init_origins[b * 3 + 1], oz = init_origins[b * 3 + 2];
        for (int t = 0; t < Tn; t++) {
            int done = done_flags[b * Tn + t];
            int upd  = upd_flags[b * Tn + t];
            if (done) {
                lx = 600.0f; ly = 600.0f; lz = 0.0f;
                gx = 2400.0f; gy = 2400.0f; gz = 0.0f;
                b0 = 360; b1 = 600; b2i = 360; b3 = 600;
                ox = 1800.0f; oy = 1800.0f; oz = 0.0f;
            }
            float th = lz * DEG2RADf;
            float c = cosf(th), sn = sinf(th);
            float d0 = pose_delta[(b * Tn + t) * 3 + 0];
            float d1 = pose_delta[(b * Tn + t) * 3 + 1];
            float d2 = pose_delta[(b * Tn + t) * 3 + 2];
            lx = lx + (d0 * c - d1 * sn);
            ly = ly + (d0 * sn + d1 * c);
            lz = lz + d2;
            if (upd) { gx = lx + ox; gy = ly + oy; gz = lz + oz; }
            out_lp[(b * Tn + t) * 3 + 0] = lx;
            out_lp[(b * Tn + t) * 3 + 1] = ly;
            out_lp[(b * Tn + t) * 3 + 2] = lz;
            out_gp[(b * Tn + t) * 3 + 0] = gx;
            out_gp[(b * Tn + t) * 3 + 1] = gy;
            out_gp[(b * Tn + t) * 3 + 2] = gz;
            out_bnds[(b * Tn + t) * 4 + 0] = (float)b0;
            out_bnds[(b * Tn + t) * 4 + 1] = (float)b1;
            out_bnds[(b * Tn + t) * 4 + 2] = (float)b2i;
            out_bnds[(b * Tn + t) * 4 + 3] = (float)b3;
            out_orgs[(b * Tn + t) * 3 + 0] = ox;
            out_orgs[(b * Tn + t) * 3 + 1] = oy;
            out_orgs[(b * Tn + t) * 3 + 2] = oz;
        }
    }

    int g = blockIdx.x * 256 + threadIdx.x;
    if (g >= Pn) return;
    int p = g % HWn;
    int tb = g / HWn;
    int b = tb % Bn;
    int t = tb / Bn;
    int h = p / Wn, w = p % Wn;
    const float* ob = obs + (size_t)((b * Tn + t) * MAP_CHn) * HWn;
    float depth = ob[3 * HWn + p] * 400.0f + 50.0f;
    float u = (float)w - 80.0f;
    float v = 60.0f - (float)h;
    float px = u * depth / fx;
    float py = v * depth / fx;
    float pz = depth;
    const float* Tm = cam + (size_t)(b * Tn + t) * 16;
    float X = ((Tm[0] * px + Tm[1] * py) + Tm[2] * pz) + Tm[3];
    float Y = ((Tm[4] * px + Tm[5] * py) + Tm[6] * pz) + Tm[7];
    float Z = ((Tm[8] * px + Tm[9] * py) + Tm[10] * pz) + Tm[11];
    float x_f = Z;
    float y_l = -X;
    float z_u = Y + 88.0f;
    float lx, ly, lz;
    pose_upto(pose_delta, done_flags, init_lpose, b, t, lx, ly, lz);
    float th2 = lz * DEG2RADf;
    float c2 = cosf(th2), s2 = sinf(th2);
    float wx = (lx + x_f * c2) - y_l * s2;
    float wy = (ly + x_f * s2) + y_l * c2;
    int ix = (int)floorf(wx / 5.0f);
    int iy = (int)floorf(wy / 5.0f);
    bool valid = (depth > 25.0f) && (depth < 500.0f) &&
                 (ix >= 0) && (ix < LOCAL_Mn) && (iy >= 0) && (iy < LOCAL_Mn);
    int cell = -1;
    if (valid) {
        cell = (t * Bn + b) * M2n + iy * LOCAL_Mn + ix;
        unsigned addv = 1u + ((z_u > 25.0f && z_u < 150.0f) ? 65536u : 0u);
        atomicAdd(&rec2[cell].x, addv);   // n in bits 0-15, obst_n in 16-30
    }
    cellid[g] = cell;
}

// Scan: per-1024-cell tile local exclusive scan -> rec2[].y; tile base claimed
// with ONE atomicAdd on a global counter (segment order across tiles is
// irrelevant — only disjointness matters).
__global__ void scan1_kernel(uint2* __restrict__ rec2,
                             unsigned* __restrict__ bsum,
                             unsigned* __restrict__ cntr) {
    __shared__ unsigned s[256];
    int tid = threadIdx.x;
    int base = blockIdx.x * 1024 + tid * 4;
    unsigned v0 = rec2[base].x & 0xFFFFu, v1 = rec2[base + 1].x & 0xFFFFu;
    unsigned v2 = rec2[base + 2].x & 0xFFFFu, v3 = rec2[base + 3].x & 0xFFFFu;
    unsigned tsum = v0 + v1 + v2 + v3;
    s[tid] = tsum;
    __syncthreads();
    for (int d = 1; d < 256; d <<= 1) {
        unsigned a = (tid >= d) ? s[tid - d] : 0u;
        __syncthreads();
        s[tid] += a;
        __syncthreads();
    }
    unsigned excl = s[tid] - tsum;
    if (tid == 255) bsum[blockIdx.x] = atomicAdd(cntr, s[255]);
    rec2[base].y     = excl;
    rec2[base + 1].y = excl + v0;
    rec2[base + 2].y = excl + v0 + v1;
    rec2[base + 3].y = excl + v0 + v1 + v2;
}

// Blocks [0, PROJ_BLKS): per-pixel scatter of 64B sem records into binned
// segments (regular stores — re-read by update, keep in L2).
// Blocks [PROJ_BLKS, +GMAP_HBLKS): lower half of the outside-window gmap copy
// — independent BW work back-filling CUs behind the scattered writes.
__global__ void __launch_bounds__(256)
scatter_copy_kernel(const float* __restrict__ obs,
                    const int* __restrict__ cellid,
                    const unsigned* __restrict__ bsum,
                    uint2* __restrict__ rec2,
                    float* __restrict__ recb,
                    const int* __restrict__ init_bounds,
                    const int* __restrict__ done_flags,
                    const float* __restrict__ init_gmap,
                    float* __restrict__ out_gmap) {
    if (blockIdx.x >= PROJ_BLKS) {
        size_t i4 = (size_t)(blockIdx.x - PROJ_BLKS) * 256 + threadIdx.x;
        if (i4 >= GMAP_HALF4) return;
        gmap_copy_i4(i4, init_bounds, done_flags, init_gmap, out_gmap);
        return;
    }
    int g = blockIdx.x * 256 + threadIdx.x;
    if (g >= Pn) return;
    int c = cellid[g];
    if (c < 0) return;
    int p = g % HWn;
    int tb = g / HWn;
    int b = tb % Bn;
    int t = tb / Bn;
    const float* ob = obs + (size_t)((b * Tn + t) * MAP_CHn) * HWn;
    vf4 r[4];
#pragma unroll
    for (int q = 0; q < 4; q++) {
        r[q].x = ob[(size_t)(NON_SEMn + 4 * q + 0) * HWn + p];
        r[q].y = ob[(size_t)(NON_SEMn + 4 * q + 1) * HWn + p];
        r[q].z = ob[(size_t)(NON_SEMn + 4 * q + 2) * HWn + p];
        r[q].w = ob[(size_t)(NON_SEMn + 4 * q + 3) * HWn + p];
    }
    unsigned pos = bsum[c >> 10] + atomicAdd(&rec2[c].y, 1u);
    vf4* rp = (vf4*)(recb + (size_t)pos * CATn);
#pragma unroll
    for (int q = 0; q < 4; q++) rp[q] = r[q];
}

// ---------------- update half (templated channel split) --------------------
// Q=0: map ch 0..11 (non-sem 0-3 + sem cats 0..7), pose/agent logic, feats
//      ch 0..15. Q=1: map ch 12..19 (sem cats 8..15), feats ch 16..23.
template <int Q>
__device__ __forceinline__ void update_half(
        int b, int j,
        const uint2* __restrict__ rec2,
        const unsigned* __restrict__ bsum,
        const float* __restrict__ recb,
        const int* __restrict__ done_flags,
        const int* __restrict__ upd_flags,
        const float* __restrict__ pose_delta,
        const float* __restrict__ init_lpose,
        const float* __restrict__ init_lmap,
        const float* __restrict__ init_gmap,
        int y1, int x1,
        float* __restrict__ out_feats,
        float* __restrict__ out_lmap,
        float* __restrict__ out_gmap) {
#pragma clang fp contract(off)
    constexpr int CH0 = Q ? 12 : 0;
    constexpr int NCH = Q ? 8 : 12;
    int y = j / LOCAL_Mn, x = j % LOCAL_Mn;

    float lm[NCH], cr[NCH];
#pragma unroll
    for (int i = 0; i < NCH; i++)
        lm[i] = __builtin_nontemporal_load(init_lmap + ((size_t)(b * MAP_CHn + CH0 + i)) * M2n + j);
#pragma unroll
    for (int i = 0; i < NCH; i++)
        cr[i] = __builtin_nontemporal_load(
            init_gmap + ((size_t)(b * MAP_CHn + CH0 + i) * GLOBAL_Mn + (y1 + y)) * GLOBAL_Mn + (x1 + x));

    // prefetch all 8 step records + segment starts (independent loads)
    uint2 rc8[Tn];
#pragma unroll
    for (int t = 0; t < Tn; t++) rc8[t] = rec2[(t * Bn + b) * M2n + j];
    unsigned st8[Tn];
#pragma unroll
    for (int t = 0; t < Tn; t++) {
        unsigned n = rc8[t].x & 0xFFFFu;
        st8[t] = bsum[((t * Bn + b) * M2n + j) >> 10] + rc8[t].y - n;
    }

    float lx = 0.0f, ly = 0.0f, lz = 0.0f;
    if (Q == 0) {
        lx = init_lpose[b * 3 + 0];
        ly = init_lpose[b * 3 + 1];
        lz = init_lpose[b * 3 + 2];
    }

    for (int t = 0; t < Tn; t++) {
        int done = done_flags[b * Tn + t];
        int upd  = upd_flags[b * Tn + t];
        if (done) {
#pragma unroll
            for (int i = 0; i < NCH; i++) { lm[i] = 0.0f; cr[i] = 0.0f; }
        }
        unsigned n = rc8[t].x & 0xFFFFu;

        if (Q == 0) {
            if (done) { lx = 600.0f; ly = 600.0f; lz = 0.0f; }
            float th = lz * DEG2RADf;
            float c = cosf(th), sn = sinf(th);
            float d0 = pose_delta[(b * Tn + t) * 3 + 0];
            float d1 = pose_delta[(b * Tn + t) * 3 + 1];
            float d2p = pose_delta[(b * Tn + t) * 3 + 2];
            lx = lx + (d0 * c - d1 * sn);
            ly = ly + (d0 * sn + d1 * c);
            lz = lz + d2p;
            float dxg = (float)x - lx / 5.0f;
            float dyg = (float)y - ly / 5.0f;
            float d2 = dxg * dxg + dyg * dyg;
            lm[0] = fmaxf(lm[0], (rc8[t].x >> 16) ? 1.0f : 0.0f);
            lm[1] = fmaxf(lm[1], n ? 1.0f : 0.0f);
            lm[2] = (d2 <= 4.0f) ? 1.0f : 0.0f;
            lm[3] = fmaxf(lm[3], (d2 <= 9.0f) ? 1.0f : 0.0f);
        }

        if (n) {
            float sem[8];
#pragma unroll
            for (int c = 0; c < 8; c++) sem[c] = 0.0f;
            // software-pipelined gather: issue record k+1's loads before
            // accumulating record k so loads stay in flight.
            const vf4* rp = (const vf4*)(recb + (size_t)st8[t] * CATn) + (Q ? 2 : 0);
            vf4 a0 = rp[0], a1 = rp[1];
            for (unsigned k = 1; k < n; k++) {
                rp += 4;
                vf4 b0 = rp[0], b1 = rp[1];
                sem[0] += a0.x; sem[1] += a0.y; sem[2] += a0.z; sem[3] += a0.w;
                sem[4] += a1.x; sem[5] += a1.y; sem[6] += a1.z; sem[7] += a1.w;
                a0 = b0; a1 = b1;
            }
            sem[0] += a0.x; sem[1] += a0.y; sem[2] += a0.z; sem[3] += a0.w;
            sem[4] += a1.x; sem[5] += a1.y; sem[6] += a1.z; sem[7] += a1.w;
            constexpr int L0 = Q ? 0 : 4;   // lm index of first sem channel
#pragma unroll
            for (int c = 0; c < 8; c++)
                lm[L0 + c] = fmaxf(lm[L0 + c], fminf(fmaxf(sem[c], 0.0f), 1.0f));
        }
        if (upd) {
#pragma unroll
            for (int i = 0; i < NCH; i++) cr[i] = fmaxf(cr[i], lm[i]);
        }

        size_t fb = ((size_t)(b * Tn + t) * FEAT_CHn) * M2n + j;
        if (Q == 0) {
#pragma unroll
            for (int i = 0; i < 4; i++)
                __builtin_nontemporal_store(lm[i], out_feats + fb + (size_t)i * M2n);
#pragma unroll
            for (int i = 0; i < 4; i++)
                __builtin_nontemporal_store(cr[i], out_feats + fb + (size_t)(4 + i) * M2n);
#pragma unroll
            for (int i = 0; i < 8; i++)
                __builtin_nontemporal_store(lm[4 + i], out_feats + fb + (size_t)(8 + i) * M2n);
        } else {
#pragma unroll
            for (int i = 0; i < 8; i++)
                __builtin_nontemporal_store(lm[i], out_feats + fb + (size_t)(16 + i) * M2n);
        }
    }

#pragma unroll
    for (int i = 0; i < NCH; i++)
        __builtin_nontemporal_store(lm[i], out_lmap + ((size_t)(b * MAP_CHn + CH0 + i)) * M2n + j);
#pragma unroll
    for (int i = 0; i < NCH; i++)
        __builtin_nontemporal_store(
            cr[i], out_gmap + ((size_t)(b * MAP_CHn + CH0 + i) * GLOBAL_Mn + (y1 + y)) * GLOBAL_Mn + (x1 + x));
}

// Mega kernel: blocks [0, UPD2_BLKS) run the split per-cell update (dispatched
// FIRST so the critical chain starts immediately); blocks after stream the
// UPPER half of the outside-window global map.
__global__ void __launch_bounds__(256)
mega_kernel(const uint2* __restrict__ rec2,
            const unsigned* __restrict__ bsum,
            const float* __restrict__ recb,
            const int* __restrict__ done_flags,
            const int* __restrict__ upd_flags,
            const float* __restrict__ pose_delta,
            const float* __restrict__ init_lpose,
            const float* __restrict__ init_lmap,
            const float* __restrict__ init_gmap,
            const int* __restrict__ init_bounds,
            float* __restrict__ out_feats,
            float* __restrict__ out_lmap,
            float* __restrict__ out_gmap) {
    if (blockIdx.x >= UPD2_BLKS) {
        size_t i4 = GMAP_HALF4 + (size_t)(blockIdx.x - UPD2_BLKS) * 256 + threadIdx.x;
        if (i4 >= GMAP_TOT4) return;
        gmap_copy_i4(i4, init_bounds, done_flags, init_gmap, out_gmap);
        return;
    }

    int idx = blockIdx.x * 256 + threadIdx.x;
    int q = idx / BMn;            // 0 or 1 — wave-uniform (BMn = 900*256)
    int cid = idx - q * BMn;
    int b = cid / M2n, j = cid % M2n;
    int y1 = init_bounds[b * 4 + 0];
    int x1 = init_bounds[b * 4 + 2];
    if (q == 0)
        update_half<0>(b, j, rec2, bsum, recb, done_flags, upd_flags,
                       pose_delta, init_lpose, init_lmap, init_gmap,
                       y1, x1, out_feats, out_lmap, out_gmap);
    else
        update_half<1>(b, j, rec2, bsum, recb, done_flags, upd_flags,
                       pose_delta, init_lpose, init_lmap, init_gmap,
                       y1, x1, out_feats, out_lmap, out_gmap);
}

// ---------------- launch ----------------
extern "C" void kernel_launch(void* const* d_in, const int* in_sizes, int n_in,
                              void* d_out, int out_size, void* d_ws, size_t ws_size,
                              hipStream_t stream) {
    const float* obs        = (const float*)d_in[0];
    const float* pose_delta = (const float*)d_in[1];
    const int*   done_flags = (const int*)d_in[2];
    const int*   upd_flags  = (const int*)d_in[3];
    const float* cam_poses  = (const float*)d_in[4];
    const float* init_lmap  = (const float*)d_in[5];
    const float* init_gmap  = (const float*)d_in[6];
    const float* init_lpose = (const float*)d_in[7];
    const float* init_gpose = (const float*)d_in[8];
    const int*   init_bnds  = (const int*)d_in[9];
    const float* init_orgs  = (const float*)d_in[10];

    float* out = (float*)d_out;
    float* ws  = (float*)d_ws;

    unsigned* cntr   = (unsigned*)(ws + WS_CNTR);
    uint2*    rec2   = (uint2*)(ws + WS_REC2);
    unsigned* bsum   = (unsigned*)(ws + WS_BSUM);
    int*      cellid = (int*)(ws + WS_CELL);
    float*    recb   = ws + WS_RECB;

    float fx = (float)(160.0 / (2.0 * tan(79.0 * M_PI / 180.0 / 2.0)));

    // zero counter (dword 96) through rec2 (ends at 128 + 2*TBM)
    (void)hipMemsetAsync(ws + WS_CNTR, 0,
                         (size_t)(32 + 2 * TBMn) * sizeof(float), stream);

    project_kernel<<<PROJ_BLKS, 256, 0, stream>>>(
        obs, cam_poses, pose_delta, done_flags, upd_flags,
        init_lpose, init_gpose, init_bnds, init_orgs,
        rec2, cellid,
        out + OUT_LP, out + OUT_GP, out + OUT_BNDS, out + OUT_ORGS, fx);

    scan1_kernel<<<NTILE_SCAN, 256, 0, stream>>>(rec2, bsum, cntr);

    scatter_copy_kernel<<<PROJ_BLKS + GMAP_HBLKS, 256, 0, stream>>>(
        obs, cellid, bsum, rec2, recb,
        init_bnds, done_flags, init_gmap, out + OUT_GMAP);

    mega_kernel<<<UPD2_BLKS + GMAP_HBLKS, 256, 0, stream>>>(
        rec2, bsum, recb, done_flags, upd_flags, pose_delta, init_lpose,
        init_lmap, init_gmap, init_bnds,
        out + OUT_FEATS, out + OUT_LMAP, out + OUT_GMAP);
}